// Round 9
// baseline (254.636 us; speedup 1.0000x reference)
//
#include <hip/hip_runtime.h>
#include <math.h>

#define DEV __device__ __forceinline__

typedef __attribute__((ext_vector_type(8))) short short8;
typedef __attribute__((ext_vector_type(4))) short short4v;
typedef __attribute__((ext_vector_type(4))) float f32x4;
typedef __attribute__((ext_vector_type(2))) unsigned uint2v;

// LDS row stride in shorts (272 B = 68 words; 68 mod 32 = 4 -> b128 reads
// land 2-way on banks = free per m136).
#define SSTR 136
#define ROWB (16 * SSTR * 2)   // 4352 B per 16-row tile

DEV short f2bf(float f) {
    unsigned u = __builtin_bit_cast(unsigned, f);
    unsigned r = (u + 0x7fffu + ((u >> 16) & 1u)) >> 16;
    return (short)r;
}

#if __has_builtin(__builtin_amdgcn_cvt_pk_bf16_f32)
DEV unsigned pk2bf(float a, float b) {
    auto v = __builtin_amdgcn_cvt_pk_bf16_f32(a, b);
    return __builtin_bit_cast(unsigned, v);
}
#else
DEV unsigned pk2bf(float a, float b) {
    return ((unsigned)(unsigned short)f2bf(a)) |
           (((unsigned)(unsigned short)f2bf(b)) << 16);
}
#endif

DEV float bfu(short s) {
    unsigned u = ((unsigned)(unsigned short)s) << 16;
    return __builtin_bit_cast(float, u);
}

// ---------------------------------------------------------------------------
// emb f32 [V][100] -> bf16 [V][112], cols 100..111 zeroed. 8 rows/block.
// ---------------------------------------------------------------------------
__global__ __launch_bounds__(256) void emb_cvt_kernel(
    const float* __restrict__ emb, short* __restrict__ embT) {
    int t = threadIdx.x;
    int row = blockIdx.x * 8 + (t >> 5);
    int c4 = t & 31;
    if (c4 >= 28) return;
    short4v v = {0, 0, 0, 0};
    if (c4 < 25) {
        f32x4 e = *(const f32x4*)&emb[row * 100 + c4 * 4];
#pragma unroll
        for (int r = 0; r < 4; ++r) v[r] = f2bf(e[r]);
    }
    *(short4v*)&embT[row * 112 + c4 * 4] = v;
}

// ---------------------------------------------------------------------------
// Pack conv weights into MFMA A-fragment order.
// mode 0 (3-tap): 13 octets per tap -> kappa: oct=kk>>3, dk=oct/13,
//   c=(oct-13*dk)*8+(kk&7); K = 320 (10 ks), oct 39 zero.
// mode 1 (conv3 loc half): kappa = c (cols 100..199 of w[100][200]), K 128.
// ---------------------------------------------------------------------------
__global__ __launch_bounds__(64) void pack_all_kernel(
    const float* __restrict__ c1w, const float* __restrict__ c2w,
    const float* __restrict__ liw, const float* __restrict__ c3w,
    short* __restrict__ A1, short* __restrict__ A2,
    short* __restrict__ A3, short* __restrict__ A4) {
    int bx = blockIdx.x;
    const float* w; short* dst; int mode, lbx;
    if (bx < 70)       { w = c1w; dst = A1; mode = 0; lbx = bx; }
    else if (bx < 140) { w = c2w; dst = A2; mode = 0; lbx = bx - 70; }
    else if (bx < 210) { w = liw; dst = A3; mode = 0; lbx = bx - 140; }
    else               { w = c3w; dst = A4; mode = 1; lbx = bx - 210; }
    int lane = threadIdx.x;
    int f = lbx % 7 * 16 + (lane & 15);
    int kb = (lbx / 7) * 32 + (lane >> 4) * 8;
    short8 v;
#pragma unroll
    for (int j = 0; j < 8; ++j) {
        int kk = kb + j;
        float val = 0.f;
        if (f < 100) {
            if (mode == 0) {
                int oct = kk >> 3, dk = oct / 13;
                int c = (oct - 13 * dk) * 8 + (kk & 7);
                if (dk < 3 && c < 100) val = w[(f * 100 + c) * 3 + dk];
            } else {
                if (kk < 100) val = w[f * 200 + 100 + kk];
            }
        }
        v[j] = f2bf(val);
    }
    *(short8*)&dst[(lbx * 64 + lane) * 8] = v;
}

// ---------------------------------------------------------------------------
// One 3-tap conv pass, BALANCED tile: this wave owns mt [MTB,MTB+MT) x
// nt [NTB,NTB+NT). Accumulator init = bias. CLAMPL: nt==4 tile reads
// clamped rows (feeds only discarded outputs). EDGE: l-range zeroing only
// in bx 0/7. POOL: relu partial sums for l in [l0,l0+64) -> hpart_slot.
// ---------------------------------------------------------------------------
template<int MT, int NT, int MTB, int NTB, bool CLAMPL, bool POOL,
         bool TO_GLOBAL, bool EDGE>
DEV void ctap(const short* __restrict__ Ap, const short* s_src, short* s_dst,
              short* __restrict__ gout, const int* bofs, const int* bofs4,
              const float* __restrict__ bias, int row0l, int l0,
              float* __restrict__ hpart_slot, int lane) {
    const int q = lane >> 4, n = lane & 15;
    const f32x4 z4 = {0.f, 0.f, 0.f, 0.f};
    f32x4 acc[MT][NT];
#pragma unroll
    for (int mt = 0; mt < MT; ++mt) {
        int fb = (MTB + mt) * 16 + q * 4;
        f32x4 bs = (fb < 100) ? *(const f32x4*)&bias[fb] : z4;
#pragma unroll
        for (int nt = 0; nt < NT; ++nt) acc[mt][nt] = bs;
    }
#pragma unroll
    for (int ks = 0; ks < 10; ++ks) {
        short8 a[MT];
#pragma unroll
        for (int mt = 0; mt < MT; ++mt)
            a[mt] = *(const short8*)&Ap[(ks * 448 + (MTB + mt) * 64 + lane) * 8];
        const char* bp = (const char*)s_src + bofs[ks];
        short8 bf[NT];
#pragma unroll
        for (int nt = 0; nt < NT; ++nt) {
            if (CLAMPL && (NTB + nt) == 4)
                bf[nt] = *(const short8*)((const char*)s_src + bofs4[ks]);
            else
                bf[nt] = *(const short8*)(bp + (NTB + nt) * ROWB);
        }
#pragma unroll
        for (int mt = 0; mt < MT; ++mt)
#pragma unroll
            for (int nt = 0; nt < NT; ++nt)
                acc[mt][nt] = __builtin_amdgcn_mfma_f32_16x16x32_bf16(
                    a[mt], bf[nt], acc[mt][nt], 0, 0, 0);
    }
    f32x4 ps[MT];
    if constexpr (POOL) {
#pragma unroll
        for (int mt = 0; mt < MT; ++mt) ps[mt] = z4;
    }
#pragma unroll
    for (int nt = 0; nt < NT; ++nt) {
        const int j = (NTB + nt) * 16 + n;
        const int l = row0l + j;
        bool lok = true;
        if constexpr (EDGE) lok = ((unsigned)l < 512u);
        const bool pok = POOL && (l >= l0) && (l < l0 + 64);
#pragma unroll
        for (int mt = 0; mt < MT; ++mt) {
            const int fb = (MTB + mt) * 16 + q * 4;
            f32x4 v;
#pragma unroll
            for (int r = 0; r < 4; ++r) {
                v[r] = fmaxf(acc[mt][nt][r], 0.f);
                if constexpr (EDGE) v[r] = lok ? v[r] : 0.f;
            }
            if constexpr (POOL) {
                if (pok) {
#pragma unroll
                    for (int r = 0; r < 4; ++r) ps[mt][r] += v[r];
                }
            }
            uint2v pk;
            pk[0] = pk2bf(v[0], v[1]); pk[1] = pk2bf(v[2], v[3]);
            if constexpr (TO_GLOBAL) {
                *(uint2v*)&gout[j * 112 + fb] = pk;
            } else {
                if ((NTB + nt) < 4 || n < 6)      // store rows j < 70 only
                    *(uint2v*)&s_dst[j * SSTR + fb] = pk;
            }
        }
    }
    if constexpr (POOL) {
#pragma unroll
        for (int mt = 0; mt < MT; ++mt)
#pragma unroll
            for (int off = 1; off <= 8; off <<= 1)
#pragma unroll
                for (int r = 0; r < 4; ++r)
                    ps[mt][r] += __shfl_xor(ps[mt][r], off, 64);
        if (n == 0) {
#pragma unroll
            for (int mt = 0; mt < MT; ++mt)
                *(f32x4*)&hpart_slot[(MTB + mt) * 16 + q * 4] = ps[mt];
        }
    }
}

// ---------------------------------------------------------------------------
// Fused conv1 -> conv2 -> li, 64-wide l-tile, 256 threads (4 waves).
// Balanced (mt,nt) wave tiles. LDS 39168 B -> 4 blocks/CU.
// ---------------------------------------------------------------------------
__global__ __launch_bounds__(256, 4) void fused_conv_kernel(
    const int* __restrict__ xidx, const short* __restrict__ embT,
    const short* __restrict__ A1, const short* __restrict__ A2,
    const short* __restrict__ A3,
    const float* __restrict__ b1, const float* __restrict__ b2,
    const float* __restrict__ b3,
    short* __restrict__ locT, float* __restrict__ hpart) {
    extern __shared__ char smem[];
    short* s_e = (short*)smem;                    // [72][SSTR], later c2
    short* s_h = (short*)(smem + 72 * SSTR * 2);  // [72][SSTR]
    const int tid = threadIdx.x;
    const int b = blockIdx.y, bx = blockIdx.x, l0 = bx * 64;
    const int lane = tid & 63, wv = tid >> 6;
    const int q = lane >> 4, n = lane & 15;

    // stage e: 70 rows x 14 b128 chunks (virtual 16-grid; c8>=14 skipped)
#pragma unroll
    for (int p = 0; p < 5; ++p) {
        int idx = tid + p * 256;           // 0..1279, need j<70
        int j = idx >> 4, c8 = idx & 15;
        if (j < 70 && c8 < 14) {
            int lg = l0 - 3 + j;
            short8 v = {0, 0, 0, 0, 0, 0, 0, 0};
            if (lg >= 0 && lg < 512) {
                int row = xidx[b * 512 + lg];
                v = *(const short8*)&embT[row * 112 + c8 * 8];
            }
            *(short8*)&s_e[j * SSTR + c8 * 8] = v;
        }
    }

    // per-lane B byte offsets for all 10 k-steps (row n+dk, col c0)
    int bofs[10], bofs4[10];
#pragma unroll
    for (int ks = 0; ks < 10; ++ks) {
        int oct = ks * 4 + q;
        int dk = (oct >= 39) ? 3 : (oct >= 26) ? 2 : (oct >= 13) ? 1 : 0;
        int c0 = (oct - 13 * dk) * 8;
        bofs[ks] = ((n + dk) * SSTR + c0) * 2;
        int r4 = 64 + n + dk; if (r4 > 69) r4 = 69;  // discarded rows only
        bofs4[ks] = (r4 * SSTR + c0) * 2;
    }
    float* hps = hpart + ((b * 8 + bx) * 2 + (wv & 1)) * 112;
    short* gouts = locT + ((size_t)b * 512 + l0) * 112;

    __syncthreads();
    const bool edge = (bx == 0) || (bx == 7);

#define PASS3T(Ap, SRC, DST, BIAS, R0L, PL, E)                                   \
    if (wv == 0)      ctap<4,3,0,0,false,PL,false,E>(Ap,SRC,DST,nullptr,bofs,bofs4,BIAS,R0L,l0,hps,lane); \
    else if (wv == 1) ctap<4,2,0,3,true, PL,false,E>(Ap,SRC,DST,nullptr,bofs,bofs4,BIAS,R0L,l0,hps,lane); \
    else if (wv == 2) ctap<3,3,4,0,false,PL,false,E>(Ap,SRC,DST,nullptr,bofs,bofs4,BIAS,R0L,l0,hps,lane); \
    else              ctap<3,2,4,3,true, PL,false,E>(Ap,SRC,DST,nullptr,bofs,bofs4,BIAS,R0L,l0,hps,lane);

    if (edge) {
        PASS3T(A1, s_e, s_h, b1, l0 - 2, true, true)
        __syncthreads();
        PASS3T(A2, s_h, s_e, b2, l0 - 1, false, true)
    } else {
        PASS3T(A1, s_e, s_h, b1, l0 - 2, true, false)
        __syncthreads();
        PASS3T(A2, s_h, s_e, b2, l0 - 1, false, false)
    }
    __syncthreads();
    // li: outputs l in [l0, l0+63] always valid
    if (wv == 0)      ctap<4,2,0,0,false,false,true,false>(A3,s_e,nullptr,gouts,bofs,bofs4,b3,l0,l0,hps,lane);
    else if (wv == 1) ctap<4,2,0,2,false,false,true,false>(A3,s_e,nullptr,gouts,bofs,bofs4,b3,l0,l0,hps,lane);
    else if (wv == 2) ctap<3,2,4,0,false,false,true,false>(A3,s_e,nullptr,gouts,bofs,bofs4,b3,l0,l0,hps,lane);
    else              ctap<3,2,4,2,false,false,true,false>(A3,s_e,nullptr,gouts,bofs,bofs4,b3,l0,l0,hps,lane);
#undef PASS3T
}

// ---------------------------------------------------------------------------
// conv3 (1x1, loc half) + conv4 fused -> logits. 64-l tile (8 blocks/CU,
// grid 4096 -> 2x TLP for this latency-bound kernel). Balanced:
// wv0=(4mt@0,nt0-1) wv1=(4mt@0,nt2-3) wv2=(3mt@4,nt0-1) wv3=(3mt@4,nt2-3).
// acc init = zg. LDS 64*SSTR*2 + 512 = 17920 B.
// ---------------------------------------------------------------------------
template<int MT, int MTB, int NTB, int SLOT>
DEV void c3tile(const short* s_in, float* s_part, const short* __restrict__ A4,
                const float* __restrict__ zg, const float* __restrict__ w4,
                int bb, int lane) {
    const int q = lane >> 4, n = lane & 15;
    const f32x4 z4 = {0.f, 0.f, 0.f, 0.f};
    f32x4 acc[MT][2];
#pragma unroll
    for (int mt = 0; mt < MT; ++mt) {
        int fb = (MTB + mt) * 16 + q * 4;
        f32x4 zgv = *(const f32x4*)&zg[bb * 112 + fb];  // pad entries are 0
#pragma unroll
        for (int nt = 0; nt < 2; ++nt) acc[mt][nt] = zgv;
    }
#pragma unroll
    for (int ks = 0; ks < 4; ++ks) {
        short8 a[MT];
#pragma unroll
        for (int mt = 0; mt < MT; ++mt)
            a[mt] = *(const short8*)&A4[(ks * 448 + (MTB + mt) * 64 + lane) * 8];
        int c0 = (ks * 4 + q) * 8;
        if (c0 > 104) c0 = 104;   // A zero for kappa>=100
        const char* bp = (const char*)(s_in + n * SSTR + c0);
        short8 bf[2];
#pragma unroll
        for (int nt = 0; nt < 2; ++nt)
            bf[nt] = *(const short8*)(bp + (NTB + nt) * ROWB);
#pragma unroll
        for (int mt = 0; mt < MT; ++mt)
#pragma unroll
            for (int nt = 0; nt < 2; ++nt)
                acc[mt][nt] = __builtin_amdgcn_mfma_f32_16x16x32_bf16(
                    a[mt], bf[nt], acc[mt][nt], 0, 0, 0);
    }
#pragma unroll
    for (int nt = 0; nt < 2; ++nt) {
        float part = 0.f;
#pragma unroll
        for (int mt = 0; mt < MT; ++mt) {
            const int fb = (MTB + mt) * 16 + q * 4;
            f32x4 w4v = (fb < 100) ? *(const f32x4*)&w4[fb] : z4;
#pragma unroll
            for (int r = 0; r < 4; ++r)
                part += fmaxf(acc[mt][nt][r], 0.f) * w4v[r];
        }
        part += __shfl_xor(part, 16, 64);
        part += __shfl_xor(part, 32, 64);
        if (q == 0) s_part[SLOT * 64 + (NTB + nt) * 16 + n] = part;
    }
}

__global__ __launch_bounds__(256) void conv3_logits_kernel(
    const short* __restrict__ locT, const short* __restrict__ A4,
    const float* __restrict__ zg, const float* __restrict__ w4,
    const float* __restrict__ b4, float* __restrict__ logits) {
    extern __shared__ char smem[];
    short* s_in = (short*)smem;                      // [64][SSTR]
    float* s_part = (float*)(smem + 64 * SSTR * 2);  // [2][64]
    const int tid = threadIdx.x;
    const int b = blockIdx.y, l0r = blockIdx.x * 64;
    const int lane = tid & 63, wv = tid >> 6;

    {   // stage 64 rows x 14 b128 chunks (virtual 16-grid), register-batched
        short8 tmp[4];
#pragma unroll
        for (int p = 0; p < 4; ++p) {
            int idx = tid + p * 256;
            int j = idx >> 4, c8 = idx & 15;
            if (c8 < 14)
                tmp[p] = *(const short8*)&locT[((size_t)b * 512 + l0r + j) * 112 + c8 * 8];
        }
#pragma unroll
        for (int p = 0; p < 4; ++p) {
            int idx = tid + p * 256;
            int j = idx >> 4, c8 = idx & 15;
            if (c8 < 14)
                *(short8*)&s_in[j * SSTR + c8 * 8] = tmp[p];
        }
    }
    __syncthreads();
    if (wv == 0)      c3tile<4, 0, 0, 0>(s_in, s_part, A4, zg, w4, b, lane);
    else if (wv == 1) c3tile<4, 0, 2, 0>(s_in, s_part, A4, zg, w4, b, lane);
    else if (wv == 2) c3tile<3, 4, 0, 1>(s_in, s_part, A4, zg, w4, b, lane);
    else              c3tile<3, 4, 2, 1>(s_in, s_part, A4, zg, w4, b, lane);
    __syncthreads();
    if (tid < 64)
        logits[b * 512 + l0r + tid] = s_part[tid] + s_part[64 + tid] + b4[0];
}

// ---------------------------------------------------------------------------
// Finish pool: hm = sum over 16 wave-slot partials / 512, gate MLP, fold g:
// zg[b,f] = conv3_b[f] + sum_h g[b,h] * w3[f][h]   (f>=100 -> 0)
// ---------------------------------------------------------------------------
__global__ __launch_bounds__(128) void pool_gate_kernel(
    const float* __restrict__ hpart, const float* __restrict__ gi_w,
    const float* __restrict__ gi_b, const float* __restrict__ w3,
    const float* __restrict__ b3, float* __restrict__ zg) {
    int b = blockIdx.x, tid = threadIdx.x;
    __shared__ float s_hm[112];
    __shared__ float s_g[100];
    if (tid < 112) {
        float a = 0.f;
#pragma unroll
        for (int s = 0; s < 16; ++s) a += hpart[(b * 16 + s) * 112 + tid];
        s_hm[tid] = a * (1.f / 512.f);
    }
    __syncthreads();
    if (tid < 100) {
        float a = gi_b[tid];
        for (int f = 0; f < 100; ++f) a += s_hm[f] * gi_w[tid * 100 + f];
        s_g[tid] = fmaxf(a, 0.f);
    }
    __syncthreads();
    if (tid < 112) {
        float a = 0.f;
        if (tid < 100) {
            a = b3[tid];
            for (int h = 0; h < 100; ++h) a += s_g[h] * w3[tid * 200 + h];
        }
        zg[b * 112 + tid] = a;
    }
}

// ---------------------------------------------------------------------------
// Fused sampler + distil head, one block per b, 512 THREADS (8 waves).
// Wave wv handles k = wv (and wv+8 for wv<2), wave-local shuffle softmax.
// Merge -> cs; pooled gather 16 iters/thread (bf16 embT); fc1 relu; sigmoid.
// s_csw (16 KB) aliases s_acc (14.3 KB) -- csw dead after the merge barrier.
// ---------------------------------------------------------------------------
__global__ __launch_bounds__(512) void samp_head_kernel(
    const float* __restrict__ u, const float* __restrict__ logits,
    const int* __restrict__ xidx, const short* __restrict__ embT,
    const float* __restrict__ f1w, const float* __restrict__ f1b,
    const float* __restrict__ hw, const float* __restrict__ hb,
    float* __restrict__ cs_out, float* __restrict__ out) {
    const float EPSV = 1.1920929e-07f;
    const float INVT = 1.f / 0.3f;
    int b = blockIdx.x, tid = threadIdx.x;
    int lane = tid & 63, wv = tid >> 6;
    __shared__ float s_logT[512], s_cs[512];
    __shared__ int s_x[512];
    __shared__ char s_buf[16384];           // s_csw[8][512] then s_acc[32][112]
    __shared__ float s_pool[112], s_h2[100], s_fin[8];
    float* s_csw = (float*)s_buf;
    float (*s_acc)[112] = (float(*)[112])s_buf;
    if (tid < 512) {
        s_logT[tid] = logits[b * 512 + tid] * INVT;
        s_x[tid] = xidx[b * 512 + tid];
    }
    __syncthreads();
    // wave-local softmax per k (each wave covers all 512 l as lane*8+i)
    const int nk = (wv < 2) ? 2 : 1;
    float csl[8];
#pragma unroll
    for (int i = 0; i < 8; ++i) csl[i] = 0.f;
    float lt[8];
#pragma unroll
    for (int i = 0; i < 8; ++i) lt[i] = s_logT[lane * 8 + i];
    for (int j = 0; j < nk; ++j) {
        int k = wv + 8 * j;
        f32x4 u0 = *(const f32x4*)&u[(b * 10 + k) * 512 + lane * 8];
        f32x4 u1 = *(const f32x4*)&u[(b * 10 + k) * 512 + lane * 8 + 4];
        float nz[8];
#pragma unroll
        for (int i = 0; i < 8; ++i) {
            float vv = (i < 4) ? u0[i] : u1[i - 4];
            vv = fminf(fmaxf(vv, EPSV), 1.f - EPSV);
            nz[i] = -__logf(-__logf(vv)) * INVT + lt[i];
        }
        float m = nz[0];
#pragma unroll
        for (int i = 1; i < 8; ++i) m = fmaxf(m, nz[i]);
#pragma unroll
        for (int off = 1; off <= 32; off <<= 1) m = fmaxf(m, __shfl_xor(m, off, 64));
        float e[8], s = 0.f;
#pragma unroll
        for (int i = 0; i < 8; ++i) { e[i] = __expf(nz[i] - m); s += e[i]; }
#pragma unroll
        for (int off = 1; off <= 32; off <<= 1) s += __shfl_xor(s, off, 64);
        float inv = 1.f / s;
#pragma unroll
        for (int i = 0; i < 8; ++i) csl[i] = fmaxf(csl[i], e[i] * inv);
    }
#pragma unroll
    for (int i = 0; i < 8; ++i) s_csw[wv * 512 + lane * 8 + i] = csl[i];
    __syncthreads();
    {
        float c = s_csw[tid];
#pragma unroll
        for (int w = 1; w < 8; ++w) c = fmaxf(c, s_csw[w * 512 + tid]);
        s_cs[tid] = c;
        cs_out[b * 512 + tid] = c;
    }
    __syncthreads();   // also fences the s_csw -> s_acc alias switch
    // pooled partial sums: thread (jg, c8) covers l = jg+32t, chans c8*8..+7
    int jg = tid >> 4, c8 = tid & 15;
    f32x4 pa = {0.f, 0.f, 0.f, 0.f}, pb = {0.f, 0.f, 0.f, 0.f};
    if (c8 < 14) {
#pragma unroll 4
        for (int l = jg; l < 512; l += 32) {
            int row = s_x[l];
            float cv = s_cs[l];
            short8 e8 = *(const short8*)&embT[(size_t)row * 112 + c8 * 8];
#pragma unroll
            for (int r = 0; r < 4; ++r) {
                pa[r] += cv * bfu(e8[r]);
                pb[r] += cv * bfu(e8[4 + r]);
            }
        }
    }
    __syncthreads();   // ensure all csw reads done before s_acc overwrite
    if (c8 < 14) {
        *(f32x4*)&s_acc[jg][c8 * 8] = pa;
        *(f32x4*)&s_acc[jg][c8 * 8 + 4] = pb;
    }
    __syncthreads();
    if (tid < 112) {
        float p = 0.f;
#pragma unroll
        for (int g = 0; g < 32; ++g) p += s_acc[g][tid];
        s_pool[tid] = p * (1.f / 512.f);
    }
    __syncthreads();
    if (tid < 100) {
        float a = f1b[tid];
        for (int i = 0; i < 100; ++i) a += s_pool[i] * f1w[tid * 100 + i];
        s_h2[tid] = fmaxf(a, 0.f);
    }
    __syncthreads();
    float v = (tid < 100) ? s_h2[tid] * hw[tid] : 0.f;
#pragma unroll
    for (int off = 32; off >= 1; off >>= 1) v += __shfl_xor(v, off, 64);
    if (lane == 0) s_fin[wv] = v;
    __syncthreads();
    if (tid == 0) {
        float z = hb[0];
#pragma unroll
        for (int w = 0; w < 8; ++w) z += s_fin[w];
        out[b] = 1.f / (1.f + __expf(-z));
    }
}

// ---------------------------------------------------------------------------
extern "C" void kernel_launch(void* const* d_in, const int* in_sizes, int n_in,
                              void* d_out, int out_size, void* d_ws, size_t ws_size,
                              hipStream_t stream) {
    const int*   x   = (const int*)d_in[0];
    const float* u   = (const float*)d_in[1];
    const float* emb = (const float*)d_in[2];
    const float* c1w = (const float*)d_in[3];
    const float* c1b = (const float*)d_in[4];
    const float* giw = (const float*)d_in[5];
    const float* gib = (const float*)d_in[6];
    const float* c2w = (const float*)d_in[7];
    const float* c2b = (const float*)d_in[8];
    const float* liw = (const float*)d_in[9];
    const float* lib = (const float*)d_in[10];
    const float* c3w = (const float*)d_in[11];
    const float* c3b = (const float*)d_in[12];
    const float* c4w = (const float*)d_in[13];
    const float* c4b = (const float*)d_in[14];
    const float* f1w = (const float*)d_in[15];
    const float* f1b = (const float*)d_in[16];
    const float* hww = (const float*)d_in[17];
    const float* hbb = (const float*)d_in[18];
    float* out = (float*)d_out;

    char* ws = (char*)d_ws;
    short* locT   = (short*)(ws + 0);           // [512][512][112] bf16 (58.7 MB)
    short* embT   = (short*)(ws + 58720256);    // [100000][112] bf16 (22.4 MB)
    short* A1     = (short*)(ws + 81120256);    // 10*448*16 B each
    short* A2     = (short*)(ws + 81191936);
    short* A3     = (short*)(ws + 81263616);
    short* A4     = (short*)(ws + 81335296);    // 4*448*16 B
    float* zg     = (float*)(ws + 81363968);    // [512][112]
    float* logits = (float*)(ws + 81593344);    // [512][512]
    float* hpart  = (float*)(ws + 82641920);    // [512][8][2][112]

    emb_cvt_kernel<<<12500, 256, 0, stream>>>(emb, embT);
    pack_all_kernel<<<238, 64, 0, stream>>>(c1w, c2w, liw, c3w, A1, A2, A3, A4);

    size_t smemA = 2 * 72 * SSTR * 2;            // 39168 B -> 4 blocks/CU
    fused_conv_kernel<<<dim3(8, 512), 256, smemA, stream>>>(
        x, embT, A1, A2, A3, c1b, c2b, lib, locT, hpart);
    pool_gate_kernel<<<512, 128, 0, stream>>>(hpart, giw, gib, c3w, c3b, zg);
    size_t smemB = 64 * SSTR * 2 + 2 * 64 * 4;   // 17920 B -> 8 blocks/CU
    conv3_logits_kernel<<<dim3(8, 512), 256, smemB, stream>>>(
        locT, A4, zg, c4w, c4b, logits);
    samp_head_kernel<<<512, 512, 0, stream>>>(
        u, logits, x, embT, f1w, f1b, hww, hbb, out + 512, out);
}